// Round 3
// baseline (360.149 us; speedup 1.0000x reference)
//
#include <hip/hip_runtime.h>
#include <hip/hip_bf16.h>

#define T_LEN 1024
#define D_DIM 64
#define BATCH 32

// ---------------------------------------------------------------------------
// Kernel 1: pairwise Euclidean distance, GEMM-trick.
// 64(M) x 128(N) tile, 256 threads, 8x4 micro-tile per thread. UNCHANGED
// this round (isolating dp fix; cost counters will surface next round).
// ---------------------------------------------------------------------------
#define BM 64
#define BN 128

__global__ __launch_bounds__(256, 3) void cost_kernel(const float* __restrict__ pred,
                                                      const float* __restrict__ targ,
                                                      float* __restrict__ cost) {
    const int b = blockIdx.z;
    const float* P = pred + (size_t)b * T_LEN * D_DIM;
    const float* Tg = targ + (size_t)b * T_LEN * D_DIM;
    float* C = cost + (size_t)b * T_LEN * T_LEN;
    const int row0 = blockIdx.y * BM;
    const int col0 = blockIdx.x * BN;

    __shared__ __align__(16) float ps[BM][D_DIM + 4];   // row-major, stride 68
    __shared__ __align__(16) float ts[D_DIM][BN + 4];   // k-major, stride 132
    __shared__ float p2[BM], t2[BN];

    const int tid = threadIdx.x;

#pragma unroll
    for (int it = 0; it < 4; ++it) {
        int f = tid + 256 * it;
        int row = f >> 4;
        int kc = f & 15;
        float4 v = *(const float4*)(P + (size_t)(row0 + row) * D_DIM + 4 * kc);
        *(float4*)&ps[row][4 * kc] = v;
    }
#pragma unroll
    for (int it = 0; it < 8; ++it) {
        int f = tid + 256 * it;
        int col = f >> 4;
        int kc = f & 15;
        float4 w = *(const float4*)(Tg + (size_t)(col0 + col) * D_DIM + 4 * kc);
        ts[4 * kc + 0][col] = w.x;
        ts[4 * kc + 1][col] = w.y;
        ts[4 * kc + 2][col] = w.z;
        ts[4 * kc + 3][col] = w.w;
    }
    __syncthreads();

    if (tid < 64) {
        float s = 0.0f;
        const float4* pr = (const float4*)&ps[tid][0];
#pragma unroll
        for (int q = 0; q < 16; ++q) {
            float4 v = pr[q];
            s += v.x * v.x; s += v.y * v.y; s += v.z * v.z; s += v.w * v.w;
        }
        p2[tid] = s;
    } else if (tid < 192) {
        int c = tid - 64;
        float s = 0.0f;
#pragma unroll
        for (int k = 0; k < 64; ++k) { float x = ts[k][c]; s += x * x; }
        t2[c] = s;
    }
    __syncthreads();

    const int tx = tid & 31;
    const int ty = tid >> 5;
    const int r0 = 8 * ty, c0 = 4 * tx;

    float acc[8][4];
#pragma unroll
    for (int i = 0; i < 8; ++i)
#pragma unroll
        for (int j = 0; j < 4; ++j) acc[i][j] = 0.0f;

#pragma unroll
    for (int k4 = 0; k4 < 16; ++k4) {
        float4 b0 = *(const float4*)&ts[4 * k4 + 0][c0];
        float4 b1 = *(const float4*)&ts[4 * k4 + 1][c0];
        float4 b2 = *(const float4*)&ts[4 * k4 + 2][c0];
        float4 b3 = *(const float4*)&ts[4 * k4 + 3][c0];
#pragma unroll
        for (int i = 0; i < 8; ++i) {
            float4 a = *(const float4*)&ps[r0 + i][4 * k4];
            acc[i][0] += a.x * b0.x; acc[i][1] += a.x * b0.y; acc[i][2] += a.x * b0.z; acc[i][3] += a.x * b0.w;
            acc[i][0] += a.y * b1.x; acc[i][1] += a.y * b1.y; acc[i][2] += a.y * b1.z; acc[i][3] += a.y * b1.w;
            acc[i][0] += a.z * b2.x; acc[i][1] += a.z * b2.y; acc[i][2] += a.z * b2.z; acc[i][3] += a.z * b2.w;
            acc[i][0] += a.w * b3.x; acc[i][1] += a.w * b3.y; acc[i][2] += a.w * b3.z; acc[i][3] += a.w * b3.w;
        }
    }

    float4 tt = *(const float4*)&t2[c0];
#pragma unroll
    for (int i = 0; i < 8; ++i) {
        float pa = p2[r0 + i];
        float4 o;
        o.x = sqrtf(fmaxf(pa + tt.x - 2.0f * acc[i][0], 1e-12f));
        o.y = sqrtf(fmaxf(pa + tt.y - 2.0f * acc[i][1], 1e-12f));
        o.z = sqrtf(fmaxf(pa + tt.z - 2.0f * acc[i][2], 1e-12f));
        o.w = sqrtf(fmaxf(pa + tt.w - 2.0f * acc[i][3], 1e-12f));
        *(float4*)(C + (size_t)(row0 + r0 + i) * T_LEN + (col0 + c0)) = o;
    }
}

// ---------------------------------------------------------------------------
// Kernel 2: Frechet DP, one wave per batch, time-skewed pipeline.
// Register pipeline (PD=8 slots x 4 float4 = 128 VGPR — occupancy is
// irrelevant here: 1 wave on each of 32 CUs) filled by inline-asm
// global_load_dwordx4 (invisible to the compiler's waitcnt pass -> no
// auto-drain), consumed under counted s_waitcnt vmcnt(28) + sched_barrier.
// Recurrence uses the exact lattice identity
//   max(c, min(min(up,left),diag)) == med3(left, c, max(c, min(up,diag)))
// so the serial per-step chain is 16 dependent v_med3_f32 instead of 32
// dependent min/max; the g = max(c, min(up,diag)) terms are off-chain ILP.
// ---------------------------------------------------------------------------
#define PD 8

#define DP_LOAD4(D0, D1, D2, D3, SRC)                                         \
    asm volatile("global_load_dwordx4 %0, %4, off\n\t"                        \
                 "global_load_dwordx4 %1, %4, off offset:16\n\t"              \
                 "global_load_dwordx4 %2, %4, off offset:32\n\t"              \
                 "global_load_dwordx4 %3, %4, off offset:48"                  \
                 : "=&v"(D0), "=&v"(D1), "=&v"(D2), "=&v"(D3)                 \
                 : "v"(SRC))

__global__ __launch_bounds__(64) void dp_kernel(const float* __restrict__ cost,
                                                float* __restrict__ out) {
    const int b = blockIdx.x;
    const int t = threadIdx.x;  // lane 0..63
    const float INF = __builtin_inff();
    const float* C = cost + (size_t)b * T_LEN * T_LEN + 16 * t;

    float prev[16];
#pragma unroll
    for (int j = 0; j < 16; ++j) prev[j] = INF;
    float right_out = INF;
    float diag_feed = INF;

    float4 pipe[PD][4];  // statically indexed everywhere -> registers

    // prologue: issue loads for steps 0..PD-1 (32 dwordx4 outstanding)
#pragma unroll
    for (int d = 0; d < PD; ++d) {
        int r = d - t; r = r < 0 ? 0 : (r > T_LEN - 1 ? T_LEN - 1 : r);
        const float* src = C + (size_t)r * T_LEN;
        DP_LOAD4(pipe[d][0], pipe[d][1], pipe[d][2], pipe[d][3], src);
    }

    const int S = T_LEN + 63;                 // 1087 real steps
    const int NCH = (S + PD - 1) / PD;        // 136 chunks -> 1088 steps (tail guarded)
    int s = 0;

#define DP_STEP(U)                                                            \
    {                                                                         \
        /* oldest 4 loads (slot U, issued PD steps ago) must be complete */   \
        asm volatile("s_waitcnt vmcnt(28)" ::: "memory");                     \
        __builtin_amdgcn_sched_barrier(0);                                    \
        const float4 q0 = pipe[U][0], q1 = pipe[U][1];                        \
        const float4 q2 = pipe[U][2], q3 = pipe[U][3];                        \
        const int r = s - t;                                                  \
        float inc = __shfl_up(right_out, 1, 64);                              \
        float left = inc, diag = diag_feed;                                   \
        diag_feed = inc;                                                      \
        if (t == 0) { left = (r == 0) ? -INF : INF; diag = INF; }             \
        if (r >= 0 && r < T_LEN) {                                            \
            float cq[16] = {q0.x, q0.y, q0.z, q0.w, q1.x, q1.y, q1.z, q1.w,   \
                            q2.x, q2.y, q2.z, q2.w, q3.x, q3.y, q3.z, q3.w};  \
            float g[16];                                                      \
            g[0] = fmaxf(cq[0], fminf(prev[0], diag));                        \
            _Pragma("unroll")                                                 \
            for (int j = 1; j < 16; ++j)                                      \
                g[j] = fmaxf(cq[j], fminf(prev[j], prev[j - 1]));             \
            float v = left;                                                   \
            _Pragma("unroll")                                                 \
            for (int j = 0; j < 16; ++j) {                                    \
                v = __builtin_amdgcn_fmed3f(v, cq[j], g[j]);                  \
                prev[j] = v;                                                  \
            }                                                                 \
            right_out = v;                                                    \
        }                                                                     \
        __builtin_amdgcn_sched_barrier(0);                                    \
        {                                                                     \
            int rn = s + PD - t;                                              \
            rn = rn < 0 ? 0 : (rn > T_LEN - 1 ? T_LEN - 1 : rn);              \
            const float* src = C + (size_t)rn * T_LEN;                        \
            DP_LOAD4(pipe[U][0], pipe[U][1], pipe[U][2], pipe[U][3], src);    \
        }                                                                     \
        ++s;                                                                  \
    }

    for (int chunk = 0; chunk < NCH; ++chunk) {
        DP_STEP(0)
        DP_STEP(1)
        DP_STEP(2)
        DP_STEP(3)
        DP_STEP(4)
        DP_STEP(5)
        DP_STEP(6)
        DP_STEP(7)
    }
#undef DP_STEP

    asm volatile("s_waitcnt vmcnt(0)" ::: "memory");
    if (t == 63) atomicAdd(out, prev[15] * (1.0f / (float)BATCH));
}

// ---------------------------------------------------------------------------
// Fallback: fused DP computing distances on the fly (only if ws can't hold
// one 4 MB cost matrix). Unchanged.
// ---------------------------------------------------------------------------
__global__ __launch_bounds__(64) void dp_fused_kernel(const float* __restrict__ pred,
                                                      const float* __restrict__ targ,
                                                      float* __restrict__ out) {
    const int b = blockIdx.x;
    const int t = threadIdx.x;
    const float INF = __builtin_inff();
    const float* P = pred + (size_t)b * T_LEN * D_DIM;
    const float* T = targ + (size_t)b * T_LEN * D_DIM + (size_t)(16 * t) * D_DIM;

    float prev[16];
#pragma unroll
    for (int j = 0; j < 16; ++j) prev[j] = INF;
    float right_out = INF;
    float diag_feed = INF;

    for (int s = 0; s < T_LEN + 63; s++) {
        int r = s - t;
        float inc = __shfl_up(right_out, 1, 64);
        float left = inc, diag = diag_feed;
        diag_feed = inc;
        if (t == 0) { left = (r == 0) ? -INF : INF; diag = INF; }
        if (r >= 0 && r < T_LEN) {
            float4 pr[16];
            const float4* pp = (const float4*)(P + (size_t)r * D_DIM);
#pragma unroll
            for (int q = 0; q < 16; q++) pr[q] = pp[q];
#pragma unroll
            for (int j = 0; j < 16; j++) {
                const float4* tp = (const float4*)(T + (size_t)j * D_DIM);
                float acc = 0.0f;
#pragma unroll
                for (int q = 0; q < 16; q++) {
                    float4 tv = tp[q];
                    float dx = pr[q].x - tv.x; acc += dx * dx;
                    float dy = pr[q].y - tv.y; acc += dy * dy;
                    float dz = pr[q].z - tv.z; acc += dz * dz;
                    float dw = pr[q].w - tv.w; acc += dw * dw;
                }
                float c = sqrtf(fmaxf(acc, 1e-12f));
                float up = prev[j];
                float v = fmaxf(c, fminf(fminf(up, diag), left));
                diag = up; left = v; prev[j] = v;
            }
            right_out = left;
        }
    }
    if (t == 63) atomicAdd(out, prev[15] * (1.0f / (float)BATCH));
}

extern "C" void kernel_launch(void* const* d_in, const int* in_sizes, int n_in,
                              void* d_out, int out_size, void* d_ws, size_t ws_size,
                              hipStream_t stream) {
    const float* pred = (const float*)d_in[0];
    const float* targ = (const float*)d_in[1];
    float* out = (float*)d_out;

    hipMemsetAsync(out, 0, sizeof(float) * out_size, stream);

    const size_t per_batch = (size_t)T_LEN * T_LEN * sizeof(float);  // 4 MB
    int bpg = (int)(ws_size / per_batch);
    if (bpg > BATCH) bpg = BATCH;

    if (bpg >= 1) {
        float* cost = (float*)d_ws;
        for (int g0 = 0; g0 < BATCH; g0 += bpg) {
            int gb = (BATCH - g0) < bpg ? (BATCH - g0) : bpg;
            dim3 grid(T_LEN / BN, T_LEN / BM, gb);
            cost_kernel<<<grid, 256, 0, stream>>>(pred + (size_t)g0 * T_LEN * D_DIM,
                                                  targ + (size_t)g0 * T_LEN * D_DIM,
                                                  cost);
            dp_kernel<<<gb, 64, 0, stream>>>(cost, out);
        }
    } else {
        dp_fused_kernel<<<BATCH, 64, 0, stream>>>(pred, targ, out);
    }
}